// Round 7
// baseline (284.205 us; speedup 1.0000x reference)
//
#include <hip/hip_runtime.h>

// GAT forward, CSR-by-dst formulation:
//   h = x@W1; a[n]=h[n]·Wp[:64]; b[n]=h[n]·Wp[64:]
//   num_e = exp(leakyrelu(a[dst]+b[src]+bp))      (recomputed where needed)
//   denom[n] = sum_{e:dst=n} num_e
//   hh[n]   = h[n] / (denom[n]+1e-16)             (bf16, in-place over h rows)
//   out[n]  = sum_{e:dst=n} num_e * hh[src_e] + bias   (denom at SRC = ref quirk)
// Edges counting-sorted by dst (hist -> scan -> scatter of src only; num is
// recomputed from L2-resident a,b in the consumers): aggregate is a per-node
// register reduction, no atomics on out.

static __device__ __forceinline__ float bf2f(unsigned short u) {
    unsigned v = (unsigned)u << 16;
    return __builtin_bit_cast(float, v);
}
static __device__ __forceinline__ unsigned short f2bf(float f) {
    unsigned u = __builtin_bit_cast(unsigned, f);
    u = (u + 0x7FFFu + ((u >> 16) & 1u)) >> 16;   // round-to-nearest-even
    return (unsigned short)u;
}

// ---------------- node transform: h = x@W1, a,b projections ----------------
// 6250 blocks x 16 nodes. 4 waves/block, 4 nodes/wave, lane = output channel.
__global__ __launch_bounds__(256) void node_transform_kernel(
    const float* __restrict__ x, const float* __restrict__ W1,
    const float* __restrict__ Wp,
    float* __restrict__ h, float* __restrict__ aArr, float* __restrict__ bArr,
    int N)
{
    __shared__ float sW1t[64 * 132];   // [o][k], 33 KB
    const int tid = threadIdx.x;
    const int w = tid >> 6, lane = tid & 63;

    // stage transposed: flat i: k=i>>6, o=i&63 -> sW1t[o*132+k]
    for (int i = tid; i < 128 * 64; i += 256)
        sW1t[(i & 63) * 132 + (i >> 6)] = W1[i];

    const float wpa = Wp[lane];
    const float wpb = Wp[64 + lane];
    __syncthreads();

    const int n0 = __builtin_amdgcn_readfirstlane(blockIdx.x * 16 + w * 4);
    const float* xp0 = x + (size_t)n0 * 128;

    float acc[4] = {0.f, 0.f, 0.f, 0.f};
    #pragma unroll 4
    for (int k4 = 0; k4 < 32; ++k4) {
        float4 wv = *reinterpret_cast<const float4*>(&sW1t[lane * 132 + k4 * 4]);
        #pragma unroll
        for (int m = 0; m < 4; ++m) {
            float4 xv = *reinterpret_cast<const float4*>(xp0 + m * 128 + k4 * 4);
            acc[m] = fmaf(xv.x, wv.x, acc[m]);
            acc[m] = fmaf(xv.y, wv.y, acc[m]);
            acc[m] = fmaf(xv.z, wv.z, acc[m]);
            acc[m] = fmaf(xv.w, wv.w, acc[m]);
        }
    }

    #pragma unroll
    for (int m = 0; m < 4; ++m) {
        const int n = n0 + m;
        h[(size_t)n * 64 + lane] = acc[m];
        float a = acc[m] * wpa, b = acc[m] * wpb;
        #pragma unroll
        for (int off = 32; off; off >>= 1) {
            a += __shfl_down(a, off);
            b += __shfl_down(b, off);
        }
        if (lane == 0) { aArr[n] = a; bArr[n] = b; }
    }
}

// ---------------- histogram of dst ----------------
__global__ __launch_bounds__(256) void hist_kernel(
    const int* __restrict__ ei, int* __restrict__ cnt, int E)
{
    int e = blockIdx.x * blockDim.x + threadIdx.x;
    if (e >= E) return;
    atomicAdd(&cnt[ei[E + e]], 1);
}

// ---------------- 3-kernel exclusive scan over cnt[N] ----------------
__global__ __launch_bounds__(256) void scan_reduce_kernel(
    const int* __restrict__ cnt, int* __restrict__ partial, int N)
{
    __shared__ int s[256];
    const int t = threadIdx.x;
    const int base = blockIdx.x * 1024 + t * 4;
    int sum = 0;
    #pragma unroll
    for (int j = 0; j < 4; ++j) {
        int n = base + j;
        sum += (n < N) ? cnt[n] : 0;
    }
    s[t] = sum;
    __syncthreads();
    for (int off = 128; off; off >>= 1) {
        if (t < off) s[t] += s[t + off];
        __syncthreads();
    }
    if (t == 0) partial[blockIdx.x] = s[0];
}

__global__ __launch_bounds__(128) void scan_partials_kernel(
    const int* __restrict__ partial, int* __restrict__ partialOff,
    int* __restrict__ offsets, int NB, int N, int E)
{
    __shared__ int s[128];
    const int t = threadIdx.x;
    int v = (t < NB) ? partial[t] : 0;
    s[t] = v;
    __syncthreads();
    for (int off = 1; off < 128; off <<= 1) {
        int u = (t >= off) ? s[t - off] : 0;
        __syncthreads();
        s[t] += u;
        __syncthreads();
    }
    if (t < NB) partialOff[t] = s[t] - v;   // exclusive
    if (t == 0) offsets[N] = E;
}

__global__ __launch_bounds__(256) void scan_final_kernel(
    const int* __restrict__ cnt, const int* __restrict__ partialOff,
    int* __restrict__ offsets, int* __restrict__ cursor, int N)
{
    __shared__ int s[256];
    const int t = threadIdx.x;
    const int base = blockIdx.x * 1024 + t * 4;
    int c[4];
    int sum = 0;
    #pragma unroll
    for (int j = 0; j < 4; ++j) {
        int n = base + j;
        c[j] = (n < N) ? cnt[n] : 0;
        sum += c[j];
    }
    s[t] = sum;
    __syncthreads();
    for (int off = 1; off < 256; off <<= 1) {
        int u = (t >= off) ? s[t - off] : 0;
        __syncthreads();
        s[t] += u;
        __syncthreads();
    }
    int run = partialOff[blockIdx.x] + s[t] - sum;
    #pragma unroll
    for (int j = 0; j < 4; ++j) {
        int n = base + j;
        if (n < N) { offsets[n] = run; cursor[n] = run; }
        run += c[j];
    }
}

// -------- scatter: pure counting-sort of src by dst (4B payload/edge) -------
__global__ __launch_bounds__(256) void scatter_kernel(
    const int* __restrict__ ei, int* __restrict__ cursor,
    int* __restrict__ sortedSrc, int E)
{
    int e = blockIdx.x * blockDim.x + threadIdx.x;
    if (e >= E) return;
    int src = ei[e];
    int dst = ei[E + e];
    int pos = atomicAdd(&cursor[dst], 1);
    sortedSrc[pos] = src;
}

// ---------------- denom + hh: wave per node ----------------
// num recomputed from a[gw] (uniform) + b[src] (L2 gather) + bp; denom = sum;
// hh = h/denom as bf16 written in-place into the FIRST HALF of the fp32 h row.
__global__ __launch_bounds__(256) void denom_hh_kernel(
    const int* __restrict__ offsets, const int* __restrict__ sortedSrc,
    const float* __restrict__ aArr, const float* __restrict__ bArr,
    const float* __restrict__ bp, float* __restrict__ h, int N)
{
    int gw = (blockIdx.x * blockDim.x + threadIdx.x) >> 6;
    int lane = threadIdx.x & 63;
    if (gw >= N) return;
    int beg = offsets[gw], end = offsets[gw + 1];
    const float ago = aArr[gw] + bp[0];
    float s = 0.f;
    for (int e = beg + lane; e < end; e += 64) {
        float t = ago + bArr[sortedSrc[e]];
        t = (t >= 0.f) ? t : 0.2f * t;
        s += __expf(t);
    }
    #pragma unroll
    for (int off = 32; off; off >>= 1) s += __shfl_down(s, off);
    s = __shfl(s, 0);
    float inv = 1.f / (s + 1e-16f);
    float hv = h[(size_t)gw * 64 + lane];
    asm volatile("" ::: "memory");   // order read-before-aliased-write
    unsigned short* row = reinterpret_cast<unsigned short*>(h) + (size_t)gw * 128;
    row[lane] = f2bf(hv * inv);
}

// ---------------- aggregate: wave per dst node, 2 edges per gather ----------
// hh row = 64 bf16 packed in the first 32 dwords of a 64-dword fp32 row:
// row base for node s is s*64 dwords. Lanes preload 64 srcs coalesced and
// compute num in parallel (a[gw] uniform + b[src] gather + exp), then
// shfl-broadcast. half = lane>>5 picks edge j/j+1; lane&31 = channel pair.
__global__ __launch_bounds__(256) void aggregate_kernel(
    const int* __restrict__ offsets, const int* __restrict__ sortedSrc,
    const float* __restrict__ aArr, const float* __restrict__ bArr,
    const float* __restrict__ bp, const unsigned* __restrict__ hhW,
    const float* __restrict__ bias, float* __restrict__ out, int N)
{
    int gw = (blockIdx.x * blockDim.x + threadIdx.x) >> 6;
    int lane = threadIdx.x & 63;
    if (gw >= N) return;
    int beg = offsets[gw], end = offsets[gw + 1];
    const float ago = aArr[gw] + bp[0];
    const int half = lane >> 5;      // which edge of the pair-step
    const int cp = lane & 31;        // channel pair index
    float accx = 0.f, accy = 0.f;
    for (int e0 = beg; e0 < end; e0 += 64) {
        int idx = e0 + lane;
        int srcL = 0; float numL = 0.f;
        if (idx < end) {
            srcL = sortedSrc[idx];
            float t = ago + bArr[srcL];
            t = (t >= 0.f) ? t : 0.2f * t;
            numL = __expf(t);
        }
        int cnt = min(64, end - e0);
        int j = 0;
        for (; j + 8 <= cnt; j += 8) {
            #pragma unroll
            for (int u = 0; u < 4; ++u) {
                int jj = j + 2 * u + half;
                int s = __shfl(srcL, jj);
                float wv = __shfl(numL, jj);
                unsigned g = hhW[(size_t)s * 64 + cp];
                accx = fmaf(bf2f((unsigned short)(g & 0xFFFFu)), wv, accx);
                accy = fmaf(bf2f((unsigned short)(g >> 16)), wv, accy);
            }
        }
        for (; j < cnt; j += 2) {
            int jj = j + half;
            bool v = jj < cnt;
            int s = __shfl(srcL, v ? jj : j);
            float wv = v ? __shfl(numL, jj) : 0.f;
            unsigned g = hhW[(size_t)s * 64 + cp];
            accx = fmaf(bf2f((unsigned short)(g & 0xFFFFu)), wv, accx);
            accy = fmaf(bf2f((unsigned short)(g >> 16)), wv, accy);
        }
    }
    accx += __shfl_xor(accx, 32);
    accy += __shfl_xor(accy, 32);
    if (lane < 32) {
        float2 b = reinterpret_cast<const float2*>(bias)[cp];
        float2 o; o.x = accx + b.x; o.y = accy + b.y;
        reinterpret_cast<float2*>(out)[(size_t)gw * 32 + cp] = o;
    }
}

extern "C" void kernel_launch(void* const* d_in, const int* in_sizes, int n_in,
                              void* d_out, int out_size, void* d_ws, size_t ws_size,
                              hipStream_t stream) {
    const float* x    = (const float*)d_in[0];
    const int*   ei   = (const int*)d_in[1];
    // d_in[2] = rank_mapping (unused)
    const float* W1   = (const float*)d_in[3];
    const float* Wp   = (const float*)d_in[4];
    const float* bp   = (const float*)d_in[5];
    const float* bias = (const float*)d_in[6];
    float* out = (float*)d_out;

    const int N = in_sizes[0] / 128;
    const int E = in_sizes[1] / 2;
    const int NB = (N + 1023) / 1024;   // 98 for N=100000

    // workspace (4B units):
    // h[N*64] | a[N] | b[N] | cnt[N] | offsets[N+1] | cursor[N] |
    // partial[128] | partialOff[128] | sortedSrc[E]
    float* h          = (float*)d_ws;
    float* aArr       = h + (size_t)N * 64;
    float* bArr       = aArr + N;
    int*   cnt        = (int*)(bArr + N);
    int*   offsets    = cnt + N;
    int*   cursor     = offsets + (N + 1);
    int*   partial    = cursor + N;
    int*   partialOff = partial + 128;
    int*   sortedSrc  = partialOff + 128;

    hipMemsetAsync(cnt, 0, (size_t)N * sizeof(int), stream);

    node_transform_kernel<<<(N + 15) / 16, 256, 0, stream>>>(x, W1, Wp, h, aArr, bArr, N);

    hist_kernel<<<(E + 255) / 256, 256, 0, stream>>>(ei, cnt, E);

    scan_reduce_kernel<<<NB, 256, 0, stream>>>(cnt, partial, N);
    scan_partials_kernel<<<1, 128, 0, stream>>>(partial, partialOff, offsets, NB, N, E);
    scan_final_kernel<<<NB, 256, 0, stream>>>(cnt, partialOff, offsets, cursor, N);

    scatter_kernel<<<(E + 255) / 256, 256, 0, stream>>>(ei, cursor, sortedSrc, E);

    denom_hh_kernel<<<(N * 64 + 255) / 256, 256, 0, stream>>>(
        offsets, sortedSrc, aArr, bArr, bp, h, N);

    aggregate_kernel<<<(N * 64 + 255) / 256, 256, 0, stream>>>(
        offsets, sortedSrc, aArr, bArr, bp,
        reinterpret_cast<const unsigned*>(h), bias, out, N);
}